// Round 12
// baseline (44.280 us; speedup 1.0000x reference)
//
#include <hip/hip_runtime.h>
#include <hip/hip_bf16.h>

#define BB 2
#define SS 128
#define HH 1024
#define AA 256
#define CC 14
#define R_TOT (BB*SS)   // 256 rows per net

typedef float f32x4 __attribute__((ext_vector_type(4)));
typedef short short8 __attribute__((ext_vector_type(8)));
typedef unsigned short ushort8v __attribute__((ext_vector_type(8)));

struct NetP { const float *W1,*b1,*W2,*b2,*s0W,*s0b,*s1W,*s1b; };
struct AllP { NetP n[3]; };

// ws BYTE offsets (256B aligned)
#define OFF_S0   0           // [3][256][14] f32 = 43008
#define OFF_S1   43008       // ends 86016
#define OFF_MEMB 86016       // [256][1024] bf16 = 524288 -> ends 610304
#define OFF_W1T  610304      // [3][256][1024] bf16 = 1572864 -> ends 2183168
#define OFF_W2T  2183168     // [3][256][256] bf16 = 393216 -> ends 2576384
#define OFF_SWT  2576384     // [3][2][16][256] bf16 = 49152 -> ends 2625536

__device__ __forceinline__ unsigned short f2b(float x) {
    return __bfloat16_as_ushort(__float2bfloat16(x));
}

// ---------------------------------------------------------------------------
// K0: convert mem -> bf16; transpose+convert W1,W2 -> [n][k] bf16; transpose
// s0W/s1W -> [net][which][16][256] bf16 (rows 14,15 zero). (verbatim R10)
// ---------------------------------------------------------------------------
__global__ __launch_bounds__(256)
void cvt_kernel(const float* __restrict__ mem, AllP P,
                unsigned short* __restrict__ membf,
                unsigned short* __restrict__ w1t,
                unsigned short* __restrict__ w2t,
                unsigned short* __restrict__ swt)
{
    __shared__ float t[64][65];
    const int bx = blockIdx.x, tid = threadIdx.x;
    if (bx < 240) {
        const bool isW1 = bx < 192;
        const int idx  = isW1 ? bx : bx - 192;
        const int net  = isW1 ? (idx >> 6) : (idx >> 4);
        const int tile = isW1 ? (idx & 63) : (idx & 15);
        const int kt = tile >> 2, nt = tile & 3;
        const int k0 = kt*64, n0 = nt*64;
        const float* __restrict__ W = isW1 ? P.n[net].W1 : P.n[net].W2;
        #pragma unroll
        for (int p = 0; p < 4; ++p) {
            const int row = p*16 + (tid >> 4);
            const int col = (tid & 15) * 4;
            const float4 v = *(const float4*)(W + (size_t)(k0+row)*AA + n0 + col);
            t[row][col] = v.x; t[row][col+1] = v.y;
            t[row][col+2] = v.z; t[row][col+3] = v.w;
        }
        __syncthreads();
        unsigned short* __restrict__ out =
            isW1 ? (w1t + (size_t)net*AA*HH) : (w2t + (size_t)net*AA*AA);
        const int ldout = isW1 ? HH : AA;
        #pragma unroll
        for (int p = 0; p < 2; ++p) {
            const int nr = p*32 + (tid >> 3);
            const int kg = (tid & 7) * 8;
            ushort8v o;
            #pragma unroll
            for (int j = 0; j < 8; ++j) o[j] = f2b(t[kg + j][nr]);
            *(ushort8v*)(out + (size_t)(n0 + nr)*ldout + k0 + kg) = o;
        }
    } else if (bx < 368) {
        const int f = (bx - 240) * 2048 + tid * 8;
        const float4 v0 = *(const float4*)(mem + f);
        const float4 v1 = *(const float4*)(mem + f + 4);
        ushort8v o;
        o[0]=f2b(v0.x); o[1]=f2b(v0.y); o[2]=f2b(v0.z); o[3]=f2b(v0.w);
        o[4]=f2b(v1.x); o[5]=f2b(v1.y); o[6]=f2b(v1.z); o[7]=f2b(v1.w);
        *(ushort8v*)(membf + f) = o;
    } else {
        const int idx = bx - 368;          // 0..5
        const int net = idx >> 1, which = idx & 1;
        const float* __restrict__ W = which ? P.n[net].s1W : P.n[net].s0W;
        unsigned short* __restrict__ out = swt + (size_t)(net*2 + which)*16*AA;
        const int k = tid;                  // 0..255
        #pragma unroll
        for (int n = 0; n < 16; ++n)
            out[(size_t)n*AA + k] = (n < CC) ? f2b(W[(size_t)k*CC + n]) : (unsigned short)0;
    }
}

// ---------------------------------------------------------------------------
// K1: fully fused MLP via MFMA (R10 math, spill-fixed unrolls).
// 48 blocks (net x 16-row tile), 512 thr = 8 waves; wave owns 32 out cols.
// ---------------------------------------------------------------------------
__global__ __launch_bounds__(512)
void mlp_mfma(const unsigned short* __restrict__ membf,
              const unsigned short* __restrict__ w1t,
              const unsigned short* __restrict__ w2t,
              const unsigned short* __restrict__ swt,
              AllP P,
              float* __restrict__ s0o, float* __restrict__ s1o)
{
    const int net = blockIdx.x >> 4;       // 0..2
    const int rt  = blockIdx.x & 15;       // 0..15
    const int row0 = rt * 16;
    const NetP p = P.n[net];
    const int tid = threadIdx.x, lane = tid & 63;
    const int wv  = tid >> 6;              // 0..7
    const int lrow = lane & 15;
    const int lk   = (lane >> 4) * 8;
    const int drow = (lane >> 4) * 4;
    const int dcol = lane & 15;

    __shared__ __align__(16) unsigned short hidL[16][264];  // 8448 B
    __shared__ __align__(16) unsigned short outL[16][264];  // 8448 B

    // ================= phase 1: hid = relu(mem@W1 + b1) =================
    {
        const unsigned short* __restrict__ Ab =
            membf + (size_t)(row0 + lrow)*HH + lk;
        const unsigned short* __restrict__ Bb =
            w1t + (size_t)net*AA*HH + (size_t)(wv*32 + lrow)*HH + lk;

        f32x4 acc0 = {0.f,0.f,0.f,0.f}, acc1 = {0.f,0.f,0.f,0.f};
        #pragma unroll 8
        for (int ks = 0; ks < 32; ++ks) {           // bounded unroll: no spill
            const short8 a  = *(const short8*)(Ab + ks*32);
            const short8 b0 = *(const short8*)(Bb + ks*32);
            const short8 b1 = *(const short8*)(Bb + (size_t)16*HH + ks*32);
            acc0 = __builtin_amdgcn_mfma_f32_16x16x32_bf16(a, b0, acc0, 0, 0, 0);
            acc1 = __builtin_amdgcn_mfma_f32_16x16x32_bf16(a, b1, acc1, 0, 0, 0);
        }
        const int n0 = wv*32 + dcol;
        const float bv0 = p.b1[n0], bv1 = p.b1[n0 + 16];
        #pragma unroll
        for (int r = 0; r < 4; ++r) {
            hidL[drow + r][n0]      = f2b(fmaxf(acc0[r] + bv0, 0.f));
            hidL[drow + r][n0 + 16] = f2b(fmaxf(acc1[r] + bv1, 0.f));
        }
    }
    __syncthreads();

    // ================= phase 2: out2 = hid@W2 + b2 =================
    {
        const unsigned short* __restrict__ B2 =
            w2t + (size_t)net*AA*AA + (size_t)(wv*32 + lrow)*AA + lk;
        f32x4 acc0 = {0.f,0.f,0.f,0.f}, acc1 = {0.f,0.f,0.f,0.f};
        #pragma unroll 4
        for (int ks = 0; ks < 8; ++ks) {
            const short8 a  = *(const short8*)(&hidL[lrow][lk + ks*32]);
            const short8 b0 = *(const short8*)(B2 + ks*32);
            const short8 b1 = *(const short8*)(B2 + (size_t)16*AA + ks*32);
            acc0 = __builtin_amdgcn_mfma_f32_16x16x32_bf16(a, b0, acc0, 0, 0, 0);
            acc1 = __builtin_amdgcn_mfma_f32_16x16x32_bf16(a, b1, acc1, 0, 0, 0);
        }
        const int n0 = wv*32 + dcol;
        const float bv0 = p.b2[n0], bv1 = p.b2[n0 + 16];
        #pragma unroll
        for (int r = 0; r < 4; ++r) {
            outL[drow + r][n0]      = f2b(acc0[r] + bv0);
            outL[drow + r][n0 + 16] = f2b(acc1[r] + bv1);
        }
    }
    __syncthreads();

    // ================= phase 3: s0/s1 projections (waves 0,1) =================
    if (wv < 2) {
        const unsigned short* __restrict__ B3 =
            swt + (size_t)(net*2 + wv)*16*AA + (size_t)lrow*AA + lk;
        f32x4 acc = {0.f,0.f,0.f,0.f};
        #pragma unroll 4
        for (int ks = 0; ks < 8; ++ks) {
            const short8 a = *(const short8*)(&outL[lrow][lk + ks*32]);
            const short8 b = *(const short8*)(B3 + ks*32);
            acc = __builtin_amdgcn_mfma_f32_16x16x32_bf16(a, b, acc, 0, 0, 0);
        }
        if (dcol < CC) {
            float* __restrict__ dst = (wv ? s1o : s0o) + ((size_t)net*R_TOT + row0)*CC;
            const float bv = (wv ? p.s1b : p.s0b)[dcol];
            #pragma unroll
            for (int r = 0; r < 4; ++r)
                dst[(size_t)(drow + r)*CC + dcol] = acc[r] + bv;
        }
    }
}

// ---------------------------------------------------------------------------
// K2: fused prefix + output fill (unchanged — proven).
// ---------------------------------------------------------------------------
__global__ __launch_bounds__(512)
void final_kernel(const float* __restrict__ s0w, const float* __restrict__ s1w,
                  const float* __restrict__ uni, float* __restrict__ out)
{
    const int bi = blockIdx.x;        // b*S + i
    const int b = bi >> 7, i = bi & (SS-1);
    const int tid = threadIdx.x;
    const int lane = tid & 63;
    const int k    = tid & 127;
    const int wv2  = (tid >> 6) & 1;
    const int slot = tid >> 7;

    __shared__ float E[SS*CC];
    __shared__ float Qe[SS*CC];
    __shared__ float red[4][4][2];
    __shared__ float mnL[CC], sh1L[CC], uniL[CC];

    if (tid < CC) {
        sh1L[tid] = s1w[(size_t)bi*CC + tid];
        uniL[tid] = uni[tid];
    }

    const float* __restrict__ sm0b = s0w + (size_t)(2*R_TOT + b*SS)*CC;
    const float* __restrict__ sm1b = s1w + (size_t)(2*R_TOT + b*SS)*CC;

    for (int pass = 0; pass < 4; ++pass) {
        const int c = pass*4 + slot;
        float x0 = 0.f, x1 = 0.f, e = 0.f, q = 0.f;
        if (c < CC) {
            x0 = sm0b[(size_t)k*CC + c];
            x1 = sm1b[(size_t)k*CC + c];
            float m = x0;
            #pragma unroll
            for (int off = 32; off >= 1; off >>= 1) m = fmaxf(m, __shfl_xor(m, off));
            float ss = x1;
            #pragma unroll
            for (int off = 32; off >= 1; off >>= 1) ss += __shfl_xor(ss, off);
            if (lane == 0) { red[0][slot][wv2] = m; red[1][slot][wv2] = ss; }
        }
        __syncthreads();
        if (c < CC) {
            const float M = fmaxf(red[0][slot][0], red[0][slot][1]);
            e = __expf(x0 - M);
            q = e * x1;
            #pragma unroll
            for (int off = 1; off <= 32; off <<= 1) {
                const float te = __shfl_up(e, off);
                const float tq = __shfl_up(q, off);
                if (lane >= off) { e += te; q += tq; }
            }
            if (lane == 63) { red[2][slot][wv2] = e; red[3][slot][wv2] = q; }
        }
        __syncthreads();
        if (c < CC) {
            if (wv2 == 1) { e += red[2][slot][0]; q += red[3][slot][0]; }
            E [k*CC + c] = e;
            Qe[k*CC + c] = q;
            if (k == 0) mnL[c] = (red[1][slot][0] + red[1][slot][1]) * (1.f/SS);
        }
        __syncthreads();
    }

    const float* __restrict__ st1 = s1w + (size_t)(R_TOT + b*SS)*CC;
    float* __restrict__ o = out + (size_t)bi*SS*CC;
    if (tid < 448) {
        const int e0 = tid * 4;
        float v[4];
        #pragma unroll
        for (int u = 0; u < 4; ++u) {
            const int idx = e0 + u;
            const int j = idx / CC, c = idx - j*CC;
            float add;
            if (i <= j) {
                const float Ei = (i > 0) ? E [(i-1)*CC + c] : 0.f;
                const float Qi = (i > 0) ? Qe[(i-1)*CC + c] : 0.f;
                add = (Qe[j*CC + c] - Qi) / (E[j*CC + c] - Ei);
            } else {
                add = mnL[c];
            }
            v[u] = sh1L[c] + st1[idx] + uniL[c] + add;
        }
        *(float4*)&o[e0] = make_float4(v[0], v[1], v[2], v[3]);
    }
}

extern "C" void kernel_launch(void* const* d_in, const int* in_sizes, int n_in,
                              void* d_out, int out_size, void* d_ws, size_t ws_size,
                              hipStream_t stream)
{
    const float* mem = (const float*)d_in[0];
    AllP P;
    for (int n = 0; n < 3; ++n) {
        const int base = 1 + 8*n;
        P.n[n].W1  = (const float*)d_in[base+0];
        P.n[n].b1  = (const float*)d_in[base+1];
        P.n[n].W2  = (const float*)d_in[base+2];
        P.n[n].b2  = (const float*)d_in[base+3];
        P.n[n].s0W = (const float*)d_in[base+4];
        P.n[n].s0b = (const float*)d_in[base+5];
        P.n[n].s1W = (const float*)d_in[base+6];
        P.n[n].s1b = (const float*)d_in[base+7];
    }
    const float* uni = (const float*)d_in[25];
    char* wsb = (char*)d_ws;
    float* s0 = (float*)(wsb + OFF_S0);
    float* s1 = (float*)(wsb + OFF_S1);
    unsigned short* membf = (unsigned short*)(wsb + OFF_MEMB);
    unsigned short* w1t   = (unsigned short*)(wsb + OFF_W1T);
    unsigned short* w2t   = (unsigned short*)(wsb + OFF_W2T);
    unsigned short* swt   = (unsigned short*)(wsb + OFF_SWT);
    float* out = (float*)d_out;

    hipLaunchKernelGGL(cvt_kernel,   dim3(374), dim3(256), 0, stream, mem, P, membf, w1t, w2t, swt);
    hipLaunchKernelGGL(mlp_mfma,     dim3(48),  dim3(512), 0, stream, membf, w1t, w2t, swt, P, s0, s1);
    hipLaunchKernelGGL(final_kernel, dim3(BB*SS), dim3(512), 0, stream, s0, s1, uni, out);
}

// Round 13
// 31.538 us; speedup vs baseline: 1.4040x; 1.4040x over previous
//
#include <hip/hip_runtime.h>

#define BB 2
#define SS 128
#define HH 1024
#define AA 256
#define CC 14
#define R_TOT (BB*SS)   // 256 rows per net

typedef float f32x2 __attribute__((ext_vector_type(2)));

struct NetP { const float *W1,*b1,*W2,*b2,*s0W,*s0b,*s1W,*s1b; };
struct AllP { NetP n[3]; };

// ws float offsets
#define S0_OFF 0                         // [3][256][14]
#define S1_OFF (3*R_TOT*CC)

// ---------------------------------------------------------------------------
// K_A: fully fused MLP per 4-row tile (R5 champion topology) with PACKED
// fp32 FMAs (v_pk_fma_f32 via __builtin_elementwise_fma on float2):
// 16 scalar FMA/iter -> 8 packed FMA/iter. Everything else identical to R5.
// grid = net(3) * rowtile(64 of 4 rows) = 192 blocks, 512 thr = 8 waves.
// ---------------------------------------------------------------------------
__global__ __launch_bounds__(512)
void mlp_fused(const float* __restrict__ mem, AllP P,
               float* __restrict__ s0o, float* __restrict__ s1o)
{
    const int bx   = blockIdx.x;
    const int net  = bx >> 6;           // 0..2
    const int rt   = bx & 63;           // 0..63
    const int row0 = rt * 4;
    const NetP p  = P.n[net];
    const int tid  = threadIdx.x;
    const int lane = tid & 63;
    const int wv   = __builtin_amdgcn_readfirstlane(tid >> 6); // 0..7
    const int col4 = 4 * lane;          // float4 column base

    __shared__ float part[8][4][AA];    // 32 KB
    __shared__ float hidL[4][AA];       // 4 KB
    __shared__ float outL[4][AA];       // 4 KB
    __shared__ float pp[112][4];        // 1.75 KB

    // ================= layer 1 (K=1024, 128 iters/wave, packed) =============
    {
        const int k0 = wv * 128;
        const float* __restrict__ W1p = p.W1 + (size_t)k0*AA + col4;
        const float* __restrict__ m0 = mem + (size_t)(row0+0)*HH + k0;
        const float* __restrict__ m1 = mem + (size_t)(row0+1)*HH + k0;
        const float* __restrict__ m2 = mem + (size_t)(row0+2)*HH + k0;
        const float* __restrict__ m3 = mem + (size_t)(row0+3)*HH + k0;
        f32x2 a0l={0,0}, a0h={0,0}, a1l={0,0}, a1h={0,0};
        f32x2 a2l={0,0}, a2h={0,0}, a3l={0,0}, a3h={0,0};
        #pragma unroll 4
        for (int kk = 0; kk < 128; ++kk) {
            const float4 w4 = *(const float4*)(W1p + (size_t)kk*AA);
            const f32x2 wlo = {w4.x, w4.y};
            const f32x2 whi = {w4.z, w4.w};
            const float v0 = m0[kk], v1 = m1[kk], v2 = m2[kk], v3 = m3[kk]; // uniform -> s_load
            const f32x2 v0s = {v0, v0}, v1s = {v1, v1};
            const f32x2 v2s = {v2, v2}, v3s = {v3, v3};
            a0l = __builtin_elementwise_fma(v0s, wlo, a0l);
            a0h = __builtin_elementwise_fma(v0s, whi, a0h);
            a1l = __builtin_elementwise_fma(v1s, wlo, a1l);
            a1h = __builtin_elementwise_fma(v1s, whi, a1h);
            a2l = __builtin_elementwise_fma(v2s, wlo, a2l);
            a2h = __builtin_elementwise_fma(v2s, whi, a2h);
            a3l = __builtin_elementwise_fma(v3s, wlo, a3l);
            a3h = __builtin_elementwise_fma(v3s, whi, a3h);
        }
        *(float4*)&part[wv][0][col4] = make_float4(a0l.x, a0l.y, a0h.x, a0h.y);
        *(float4*)&part[wv][1][col4] = make_float4(a1l.x, a1l.y, a1h.x, a1h.y);
        *(float4*)&part[wv][2][col4] = make_float4(a2l.x, a2l.y, a2h.x, a2h.y);
        *(float4*)&part[wv][3][col4] = make_float4(a3l.x, a3l.y, a3h.x, a3h.y);
    }
    __syncthreads();
    for (int i = tid; i < 4*AA; i += 512) {
        const int r = i >> 8, u = i & (AA-1);
        float s = p.b1[u];
        #pragma unroll
        for (int w = 0; w < 8; ++w) s += part[w][r][u];
        hidL[r][u] = fmaxf(s, 0.f);
    }
    __syncthreads();

    // ================= layer 2 (K=256, 32 iters/wave, packed) ===============
    {
        const int k0 = wv * 32;
        const float* __restrict__ W2p = p.W2 + (size_t)k0*AA + col4;
        f32x2 a0l={0,0}, a0h={0,0}, a1l={0,0}, a1h={0,0};
        f32x2 a2l={0,0}, a2h={0,0}, a3l={0,0}, a3h={0,0};
        #pragma unroll 4
        for (int kk = 0; kk < 32; ++kk) {
            const float4 w4 = *(const float4*)(W2p + (size_t)kk*AA);
            const f32x2 wlo = {w4.x, w4.y};
            const f32x2 whi = {w4.z, w4.w};
            const float v0 = hidL[0][k0+kk], v1 = hidL[1][k0+kk];  // LDS broadcast
            const float v2 = hidL[2][k0+kk], v3 = hidL[3][k0+kk];
            const f32x2 v0s = {v0, v0}, v1s = {v1, v1};
            const f32x2 v2s = {v2, v2}, v3s = {v3, v3};
            a0l = __builtin_elementwise_fma(v0s, wlo, a0l);
            a0h = __builtin_elementwise_fma(v0s, whi, a0h);
            a1l = __builtin_elementwise_fma(v1s, wlo, a1l);
            a1h = __builtin_elementwise_fma(v1s, whi, a1h);
            a2l = __builtin_elementwise_fma(v2s, wlo, a2l);
            a2h = __builtin_elementwise_fma(v2s, whi, a2h);
            a3l = __builtin_elementwise_fma(v3s, wlo, a3l);
            a3h = __builtin_elementwise_fma(v3s, whi, a3h);
        }
        __syncthreads();   // all layer-1 part reads done before overwrite
        *(float4*)&part[wv][0][col4] = make_float4(a0l.x, a0l.y, a0h.x, a0h.y);
        *(float4*)&part[wv][1][col4] = make_float4(a1l.x, a1l.y, a1h.x, a1h.y);
        *(float4*)&part[wv][2][col4] = make_float4(a2l.x, a2l.y, a2h.x, a2h.y);
        *(float4*)&part[wv][3][col4] = make_float4(a3l.x, a3l.y, a3h.x, a3h.y);
    }
    __syncthreads();
    for (int i = tid; i < 4*AA; i += 512) {
        const int r = i >> 8, u = i & (AA-1);
        float s = p.b2[u];
        #pragma unroll
        for (int w = 0; w < 8; ++w) s += part[w][r][u];
        outL[r][u] = s;
    }
    __syncthreads();

    // ================= projections to C=14 (verbatim R5) =================
    if (tid < 448) {
        const int task = tid >> 2, kc = tid & 3;
        const int which = (task >= 56) ? 1 : 0;
        const int rem2  = task - which*56;
        const int rr = rem2 / CC, c = rem2 % CC;
        const float* __restrict__ W = which ? p.s1W : p.s0W;
        float s = 0.f;
        #pragma unroll 4
        for (int k = kc*64; k < kc*64 + 64; ++k)
            s = fmaf(outL[rr][k], W[(size_t)k*CC + c], s);
        pp[task][kc] = s;
    }
    __syncthreads();
    if (tid < 112) {
        const int which = (tid >= 56) ? 1 : 0;
        const int rem2  = tid - which*56;
        const int rr = rem2 / CC, c = rem2 % CC;
        const float s = pp[tid][0]+pp[tid][1]+pp[tid][2]+pp[tid][3]
                      + (which ? p.s1b : p.s0b)[c];
        (which ? s1o : s0o)[((size_t)net*R_TOT + row0 + rr)*CC + c] = s;
    }
}

// ---------------------------------------------------------------------------
// K_B: fused prefix + output fill (unchanged — proven).
// ---------------------------------------------------------------------------
__global__ __launch_bounds__(512)
void final_kernel(const float* __restrict__ s0w, const float* __restrict__ s1w,
                  const float* __restrict__ uni, float* __restrict__ out)
{
    const int bi = blockIdx.x;        // b*S + i
    const int b = bi >> 7, i = bi & (SS-1);
    const int tid = threadIdx.x;
    const int lane = tid & 63;
    const int k    = tid & 127;
    const int wv2  = (tid >> 6) & 1;
    const int slot = tid >> 7;

    __shared__ float E[SS*CC];
    __shared__ float Qe[SS*CC];
    __shared__ float red[4][4][2];
    __shared__ float mnL[CC], sh1L[CC], uniL[CC];

    if (tid < CC) {
        sh1L[tid] = s1w[(size_t)bi*CC + tid];
        uniL[tid] = uni[tid];
    }

    const float* __restrict__ sm0b = s0w + (size_t)(2*R_TOT + b*SS)*CC;
    const float* __restrict__ sm1b = s1w + (size_t)(2*R_TOT + b*SS)*CC;

    for (int pass = 0; pass < 4; ++pass) {
        const int c = pass*4 + slot;
        float x0 = 0.f, x1 = 0.f, e = 0.f, q = 0.f;
        if (c < CC) {
            x0 = sm0b[(size_t)k*CC + c];
            x1 = sm1b[(size_t)k*CC + c];
            float m = x0;
            #pragma unroll
            for (int off = 32; off >= 1; off >>= 1) m = fmaxf(m, __shfl_xor(m, off));
            float ss = x1;
            #pragma unroll
            for (int off = 32; off >= 1; off >>= 1) ss += __shfl_xor(ss, off);
            if (lane == 0) { red[0][slot][wv2] = m; red[1][slot][wv2] = ss; }
        }
        __syncthreads();
        if (c < CC) {
            const float M = fmaxf(red[0][slot][0], red[0][slot][1]);
            e = __expf(x0 - M);
            q = e * x1;
            #pragma unroll
            for (int off = 1; off <= 32; off <<= 1) {
                const float te = __shfl_up(e, off);
                const float tq = __shfl_up(q, off);
                if (lane >= off) { e += te; q += tq; }
            }
            if (lane == 63) { red[2][slot][wv2] = e; red[3][slot][wv2] = q; }
        }
        __syncthreads();
        if (c < CC) {
            if (wv2 == 1) { e += red[2][slot][0]; q += red[3][slot][0]; }
            E [k*CC + c] = e;
            Qe[k*CC + c] = q;
            if (k == 0) mnL[c] = (red[1][slot][0] + red[1][slot][1]) * (1.f/SS);
        }
        __syncthreads();
    }

    const float* __restrict__ st1 = s1w + (size_t)(R_TOT + b*SS)*CC;
    float* __restrict__ o = out + (size_t)bi*SS*CC;
    if (tid < 448) {
        const int e0 = tid * 4;
        float v[4];
        #pragma unroll
        for (int u = 0; u < 4; ++u) {
            const int idx = e0 + u;
            const int j = idx / CC, c = idx - j*CC;
            float add;
            if (i <= j) {
                const float Ei = (i > 0) ? E [(i-1)*CC + c] : 0.f;
                const float Qi = (i > 0) ? Qe[(i-1)*CC + c] : 0.f;
                add = (Qe[j*CC + c] - Qi) / (E[j*CC + c] - Ei);
            } else {
                add = mnL[c];
            }
            v[u] = sh1L[c] + st1[idx] + uniL[c] + add;
        }
        *(float4*)&o[e0] = make_float4(v[0], v[1], v[2], v[3]);
    }
}

extern "C" void kernel_launch(void* const* d_in, const int* in_sizes, int n_in,
                              void* d_out, int out_size, void* d_ws, size_t ws_size,
                              hipStream_t stream)
{
    const float* mem = (const float*)d_in[0];
    AllP P;
    for (int n = 0; n < 3; ++n) {
        const int base = 1 + 8*n;
        P.n[n].W1  = (const float*)d_in[base+0];
        P.n[n].b1  = (const float*)d_in[base+1];
        P.n[n].W2  = (const float*)d_in[base+2];
        P.n[n].b2  = (const float*)d_in[base+3];
        P.n[n].s0W = (const float*)d_in[base+4];
        P.n[n].s0b = (const float*)d_in[base+5];
        P.n[n].s1W = (const float*)d_in[base+6];
        P.n[n].s1b = (const float*)d_in[base+7];
    }
    const float* uni = (const float*)d_in[25];
    float* ws  = (float*)d_ws;
    float* s0  = ws + S0_OFF;
    float* s1  = ws + S1_OFF;
    float* out = (float*)d_out;

    hipLaunchKernelGGL(mlp_fused,    dim3(192),   dim3(512), 0, stream, mem, P, s0, s1);
    hipLaunchKernelGGL(final_kernel, dim3(BB*SS), dim3(512), 0, stream, s0, s1, uni, out);
}